// Round 1
// baseline (249.512 us; speedup 1.0000x reference)
//
#include <hip/hip_runtime.h>
#include <hip/hip_bf16.h>
#include <stdint.h>

// DeepSeek MoE: rmsnorm -> router top2 -> grouped expert FFN (2 shared + 8 routed)
// Strategy: token-gather grouped GEMM in bf16 MFMA (f32 accum), weights
// pre-transposed+converted to bf16 [G][N][K] each call.

#define NTOK 2048
#define DM   1024
#define DH   1408
#define NGRP 10
#define EPSV 1.1920928955078125e-7f
#define MAXTILES 72
#define MAXSLOTS (MAXTILES * 128)

typedef __bf16 bf16x8 __attribute__((ext_vector_type(8)));
typedef float  f32x4  __attribute__((ext_vector_type(4)));

__device__ __forceinline__ void async16(const void* g, void* l) {
  __builtin_amdgcn_global_load_lds(
      (const __attribute__((address_space(1))) unsigned*)g,
      (__attribute__((address_space(3))) unsigned*)l, 16, 0, 0);
}

__device__ __forceinline__ unsigned short f2bf(float f) {
  unsigned u = __builtin_bit_cast(unsigned, f);
  unsigned r = (u + 0x7FFFu + ((u >> 16) & 1u)) >> 16;
  return (unsigned short)r;
}
__device__ __forceinline__ float bf2f(unsigned short h) {
  unsigned u = ((unsigned)h) << 16;
  return __builtin_bit_cast(float, u);
}

// ---- transpose+convert: src f32 [G][R][C] -> dst bf16 [G][C][R] ----
__global__ __launch_bounds__(256) void transpose_conv(
    const float* __restrict__ src, unsigned short* __restrict__ dst, int R, int C) {
  __shared__ float t[32][33];
  int g = blockIdx.z;
  const float* s = src + (size_t)g * R * C;
  unsigned short* d = dst + (size_t)g * R * C;
  int c0 = blockIdx.x * 32, r0 = blockIdx.y * 32;
  int tx = threadIdx.x, ty = threadIdx.y;
#pragma unroll
  for (int i = 0; i < 4; ++i)
    t[ty + i * 8][tx] = s[(size_t)(r0 + ty + i * 8) * C + c0 + tx];
  __syncthreads();
#pragma unroll
  for (int i = 0; i < 4; ++i)
    d[(size_t)(c0 + ty + i * 8) * R + r0 + tx] = f2bf(t[tx][ty + i * 8]);
}

// ---- rmsnorm: x f32 [2048][1024] -> XnF f32, XnB bf16 ----
__global__ __launch_bounds__(256) void rmsnorm_k(
    const float* __restrict__ x, const float* __restrict__ nw,
    float* __restrict__ xf, unsigned short* __restrict__ xb) {
  int t = blockIdx.x, tid = threadIdx.x;
  const float4 v = *(const float4*)(x + (size_t)t * DM + tid * 4);
  float s = v.x * v.x + v.y * v.y + v.z * v.z + v.w * v.w;
#pragma unroll
  for (int o = 32; o; o >>= 1) s += __shfl_down(s, o);
  __shared__ float ps[4];
  if ((tid & 63) == 0) ps[tid >> 6] = s;
  __syncthreads();
  float tot = ps[0] + ps[1] + ps[2] + ps[3];
  float r = rsqrtf(tot * (1.0f / (float)DM) + EPSV);
  const float4 wv = *(const float4*)(nw + tid * 4);
  float4 y;
  y.x = v.x * r * wv.x; y.y = v.y * r * wv.y; y.z = v.z * r * wv.z; y.w = v.w * r * wv.w;
  *(float4*)(xf + (size_t)t * DM + tid * 4) = y;
  ushort4 u; u.x = f2bf(y.x); u.y = f2bf(y.y); u.z = f2bf(y.z); u.w = f2bf(y.w);
  *(ushort4*)(xb + (size_t)t * DM + tid * 4) = u;
}

// ---- router: aff = Xn @ Wr^T (f32), top2, counts ----
__global__ __launch_bounds__(64) void router_k(
    const float* __restrict__ xf, const float* __restrict__ Wr,
    int* __restrict__ cnt, int* __restrict__ idx2, float* __restrict__ gate2) {
  int t = blockIdx.x, lane = threadIdx.x;
  float xv[16];
#pragma unroll
  for (int j = 0; j < 16; ++j) xv[j] = xf[(size_t)t * DM + lane + 64 * j];
  float af[8];
#pragma unroll
  for (int e = 0; e < 8; ++e) {
    const float* wr = Wr + (size_t)e * DM;
    float p = 0.f;
#pragma unroll
    for (int j = 0; j < 16; ++j) p += xv[j] * wr[lane + 64 * j];
#pragma unroll
    for (int o = 32; o; o >>= 1) p += __shfl_down(p, o);
    af[e] = p;
  }
  if (lane == 0) {
    int e1 = 0; float a1 = af[0];
#pragma unroll
    for (int e = 1; e < 8; ++e) if (af[e] > a1) { a1 = af[e]; e1 = e; }
    int e2 = -1; float a2 = -3.4e38f;
#pragma unroll
    for (int e = 0; e < 8; ++e) if (e != e1 && af[e] > a2) { a2 = af[e]; e2 = e; }
    atomicAdd(&cnt[e1], 1);
    atomicAdd(&cnt[e2], 1);
    idx2[t * 2] = e1; idx2[t * 2 + 1] = e2;
    gate2[t * 2] = a1; gate2[t * 2 + 1] = a2;
  }
}

// ---- build tile map + default slot lists ----
__global__ __launch_bounds__(256) void build_k(
    const int* __restrict__ cnt, int* __restrict__ base_slot, int* __restrict__ tile_group,
    int* __restrict__ tok_list, float* __restrict__ gate_list) {
  int tid = threadIdx.x;
  if (tid == 0) {
    for (int i = 0; i < 32; ++i) tile_group[i] = i >> 4;  // shared experts 0,1
    int tile = 32;
    for (int e = 0; e < 8; ++e) {
      base_slot[e] = tile * 128;
      int nt = (cnt[e] + 127) >> 7;
      for (int i = 0; i < nt; ++i) tile_group[tile++] = 2 + e;
    }
    for (; tile < MAXTILES; ++tile) tile_group[tile] = -1;
  }
  for (int s = tid; s < MAXSLOTS; s += 256) {
    int tok; float gv;
    if (s < 2048)      { tok = s;        gv = 1.f; }
    else if (s < 4096) { tok = s - 2048; gv = 1.f; }
    else               { tok = -1;       gv = 0.f; }
    tok_list[s] = tok; gate_list[s] = gv;
  }
}

// ---- scatter tokens into routed slots ----
__global__ __launch_bounds__(256) void place_k(
    const int* __restrict__ idx2, const float* __restrict__ gate2,
    const int* __restrict__ base_slot, int* __restrict__ fill,
    int* __restrict__ tok_list, float* __restrict__ gate_list, int* __restrict__ slot_of) {
  int t = blockIdx.x * 256 + threadIdx.x;
  if (t >= NTOK) return;
#pragma unroll
  for (int k = 0; k < 2; ++k) {
    int e = idx2[t * 2 + k];
    int pos = atomicAdd(&fill[e], 1);
    int slot = base_slot[e] + pos;
    tok_list[slot] = t;
    gate_list[slot] = gate2[t * 2 + k];
    slot_of[t * 2 + k] = slot;
  }
}

// ---- grouped GEMM: 128x128 tile, 4 waves, mfma 16x16x32 bf16 ----
template <int KD, int ND, bool FIRST>
__global__ __launch_bounds__(256) void gemm_k(
    const unsigned short* __restrict__ A, const int* __restrict__ tok_list,
    const int* __restrict__ tile_group, const unsigned short* __restrict__ Bt,
    const float* __restrict__ bias_sh, const float* __restrict__ bias_rt,
    const float* __restrict__ gate_list, unsigned short* __restrict__ Out) {
  int tile = blockIdx.x;
  int g = tile_group[tile];
  if (g < 0) return;
  int bn = blockIdx.y * 128;
  int tid = threadIdx.x;
  __shared__ unsigned short As[128 * 32];
  __shared__ unsigned short Bs[128 * 32];
  __shared__ int rows_s[128];
  __shared__ float gates_s[128];
  if (tid < 128) {
    int slot = tile * 128 + tid;
    if (FIRST) {
      int tok = tok_list[slot];
      rows_s[tid] = tok < 0 ? 0 : tok;
    } else {
      rows_s[tid] = slot;
      gates_s[tid] = gate_list[slot];
    }
  }
  __syncthreads();
  int q = tid >> 2, sg = (tid & 3) * 8;
  const unsigned short* srcA0 = A + (size_t)rows_s[q] * KD + sg;
  const unsigned short* srcA1 = A + (size_t)rows_s[64 + q] * KD + sg;
  const unsigned short* bbase = Bt + ((size_t)g * ND + bn) * KD;
  const unsigned short* srcB0 = bbase + (size_t)q * KD + sg;
  const unsigned short* srcB1 = bbase + (size_t)(64 + q) * KD + sg;
  char* lAs = (char*)As;
  char* lBs = (char*)Bs;
  f32x4 acc[4][4];
#pragma unroll
  for (int m = 0; m < 4; ++m)
#pragma unroll
    for (int n = 0; n < 4; ++n) acc[m][n] = (f32x4){0.f, 0.f, 0.f, 0.f};
  int lane = tid & 63, w = tid >> 6;
  int wr = (w >> 1) * 64, wc = (w & 1) * 64;
  int lr = lane & 15, kb = (lane >> 4) * 8;
  const unsigned short* pAf = As + (wr + lr) * 32 + kb;
  const unsigned short* pBf = Bs + (wc + lr) * 32 + kb;
  for (int kt = 0; kt < KD / 32; ++kt) {
    int k0 = kt * 32;
    async16(srcA0 + k0, lAs + tid * 16);
    async16(srcA1 + k0, lAs + 4096 + tid * 16);
    async16(srcB0 + k0, lBs + tid * 16);
    async16(srcB1 + k0, lBs + 4096 + tid * 16);
    __syncthreads();
    bf16x8 a[4], b[4];
#pragma unroll
    for (int m = 0; m < 4; ++m) a[m] = *(const bf16x8*)(pAf + m * 16 * 32);
#pragma unroll
    for (int n = 0; n < 4; ++n) b[n] = *(const bf16x8*)(pBf + n * 16 * 32);
#pragma unroll
    for (int m = 0; m < 4; ++m)
#pragma unroll
      for (int n = 0; n < 4; ++n)
        acc[m][n] = __builtin_amdgcn_mfma_f32_16x16x32_bf16(a[m], b[n], acc[m][n], 0, 0, 0);
    __syncthreads();
  }
  const float* bias = (g < 2) ? (bias_sh + (size_t)g * ND) : (bias_rt + (size_t)(g - 2) * ND);
#pragma unroll
  for (int n = 0; n < 4; ++n) {
    int gcol = bn + wc + n * 16 + lr;
    float bv = bias[gcol];
#pragma unroll
    for (int m = 0; m < 4; ++m) {
      int r0 = wr + m * 16 + (lane >> 4) * 4;
#pragma unroll
      for (int j = 0; j < 4; ++j) {
        float v = acc[m][n][j] + bv;
        if (FIRST) {
          v = v / (1.f + expf(-v));  // silu
        } else {
          v *= gates_s[r0 + j];
        }
        Out[(size_t)(tile * 128 + r0 + j) * ND + gcol] = f2bf(v);
      }
    }
  }
}

// ---- combine: out = x + O[shared0] + O[shared1] + O[slot0] + O[slot1] ----
__global__ __launch_bounds__(256) void combine_k(
    const float* __restrict__ x, const unsigned short* __restrict__ O,
    const int* __restrict__ slot_of, float* __restrict__ out) {
  int t = blockIdx.x, tid = threadIdx.x;
  int d = tid * 4;
  int s0 = slot_of[t * 2], s1 = slot_of[t * 2 + 1];
  float4 xv = *(const float4*)(x + (size_t)t * DM + d);
  ushort4 a = *(const ushort4*)(O + (size_t)t * DM + d);
  ushort4 b = *(const ushort4*)(O + (size_t)(2048 + t) * DM + d);
  ushort4 c = *(const ushort4*)(O + (size_t)s0 * DM + d);
  ushort4 e = *(const ushort4*)(O + (size_t)s1 * DM + d);
  float4 o;
  o.x = xv.x + bf2f(a.x) + bf2f(b.x) + bf2f(c.x) + bf2f(e.x);
  o.y = xv.y + bf2f(a.y) + bf2f(b.y) + bf2f(c.y) + bf2f(e.y);
  o.z = xv.z + bf2f(a.z) + bf2f(b.z) + bf2f(c.z) + bf2f(e.z);
  o.w = xv.w + bf2f(a.w) + bf2f(b.w) + bf2f(c.w) + bf2f(e.w);
  *(float4*)(out + (size_t)t * DM + d) = o;
}

extern "C" void kernel_launch(void* const* d_in, const int* in_sizes, int n_in,
                              void* d_out, int out_size, void* d_ws, size_t ws_size,
                              hipStream_t stream) {
  const float* x   = (const float*)d_in[0];
  const float* nw  = (const float*)d_in[1];
  const float* Wr  = (const float*)d_in[2];
  const float* Ws1 = (const float*)d_in[3];
  const float* bs1 = (const float*)d_in[4];
  const float* Ws2 = (const float*)d_in[5];
  const float* bs2 = (const float*)d_in[6];
  const float* W1  = (const float*)d_in[7];
  const float* b1  = (const float*)d_in[8];
  const float* W2  = (const float*)d_in[9];
  const float* b2  = (const float*)d_in[10];
  float* out = (float*)d_out;

  char* ws = (char*)d_ws;
  size_t off = 0;
  auto alloc = [&](size_t n) {
    size_t r = off;
    off += (n + 255) & ~(size_t)255;
    return r;
  };
  float*          XnF  = (float*)(ws + alloc((size_t)NTOK * DM * 4));
  unsigned short* XnB  = (unsigned short*)(ws + alloc((size_t)NTOK * DM * 2));
  unsigned short* W1t  = (unsigned short*)(ws + alloc((size_t)NGRP * DH * DM * 2));
  unsigned short* W2t  = (unsigned short*)(ws + alloc((size_t)NGRP * DM * DH * 2));
  unsigned short* Hb   = (unsigned short*)(ws + alloc((size_t)MAXSLOTS * DH * 2));
  unsigned short* Ob   = (unsigned short*)(ws + alloc((size_t)MAXSLOTS * DM * 2));
  int*   cnt       = (int*)(ws + alloc(64));  // cnt[8] + fill[8]
  int*   fill      = cnt + 8;
  int*   base_slot = (int*)(ws + alloc(32));
  int*   idx2      = (int*)(ws + alloc((size_t)NTOK * 2 * 4));
  float* gate2     = (float*)(ws + alloc((size_t)NTOK * 2 * 4));
  int*   tile_group= (int*)(ws + alloc(128 * 4));
  int*   tok_list  = (int*)(ws + alloc((size_t)MAXSLOTS * 4));
  float* gate_list = (float*)(ws + alloc((size_t)MAXSLOTS * 4));
  int*   slot_of   = (int*)(ws + alloc((size_t)NTOK * 2 * 4));

  hipMemsetAsync(cnt, 0, 64, stream);

  // weight convert+transpose: [G][K][N] f32 -> [G][N][K] bf16
  transpose_conv<<<dim3(44, 32, 2), dim3(32, 8), 0, stream>>>(Ws1, W1t, DM, DH);
  transpose_conv<<<dim3(44, 32, 8), dim3(32, 8), 0, stream>>>(W1, W1t + (size_t)2 * DH * DM, DM, DH);
  transpose_conv<<<dim3(32, 44, 2), dim3(32, 8), 0, stream>>>(Ws2, W2t, DH, DM);
  transpose_conv<<<dim3(32, 44, 8), dim3(32, 8), 0, stream>>>(W2, W2t + (size_t)2 * DM * DH, DH, DM);

  rmsnorm_k<<<NTOK, 256, 0, stream>>>(x, nw, XnF, XnB);
  router_k<<<NTOK, 64, 0, stream>>>(XnF, Wr, cnt, idx2, gate2);
  build_k<<<1, 256, 0, stream>>>(cnt, base_slot, tile_group, tok_list, gate_list);
  place_k<<<8, 256, 0, stream>>>(idx2, gate2, base_slot, fill, tok_list, gate_list, slot_of);

  gemm_k<DM, DH, true><<<dim3(MAXTILES, DH / 128), 256, 0, stream>>>(
      XnB, tok_list, tile_group, W1t, bs1, b1, nullptr, Hb);
  gemm_k<DH, DM, false><<<dim3(MAXTILES, DM / 128), 256, 0, stream>>>(
      Hb, tok_list, tile_group, W2t, bs2, b2, gate_list, Ob);

  combine_k<<<NTOK, 256, 0, stream>>>(x, Ob, slot_of, out);
}

// Round 2
// 236.242 us; speedup vs baseline: 1.0562x; 1.0562x over previous
//
#include <hip/hip_runtime.h>
#include <hip/hip_bf16.h>
#include <stdint.h>

// DeepSeek MoE: rmsnorm+router -> grouped expert FFN (2 shared + 8 routed)
// R2: 2-deep-prefetch pipelined grouped GEMM (3 LDS buffers, counted vmcnt,
// raw barriers), XCD-chunked block swizzle, fused router/build kernels.

#define NTOK 2048
#define DM   1024
#define DH   1408
#define NGRP 10
#define EPSV 1.1920928955078125e-7f
#define MAXTILES 72
#define MAXSLOTS (MAXTILES * 128)

typedef __bf16 bf16x8 __attribute__((ext_vector_type(8)));
typedef float  f32x4  __attribute__((ext_vector_type(4)));

__device__ __forceinline__ void async16(const void* g, void* l) {
  __builtin_amdgcn_global_load_lds(
      (const __attribute__((address_space(1))) unsigned*)g,
      (__attribute__((address_space(3))) unsigned*)l, 16, 0, 0);
}

__device__ __forceinline__ unsigned short f2bf(float f) {
  unsigned u = __builtin_bit_cast(unsigned, f);
  unsigned r = (u + 0x7FFFu + ((u >> 16) & 1u)) >> 16;
  return (unsigned short)r;
}
__device__ __forceinline__ float bf2f(unsigned short h) {
  unsigned u = ((unsigned)h) << 16;
  return __builtin_bit_cast(float, u);
}

// bijective XCD-chunk swizzle (m204): consecutive wg ids -> same XCD
__device__ __forceinline__ int xcd_swizzle(int id, int nwg) {
  int q = nwg >> 3, r = nwg & 7;
  int xcd = id & 7, idx = id >> 3;
  return (xcd < r ? xcd * (q + 1) : r * (q + 1) + (xcd - r) * q) + idx;
}

// ---- transpose+convert: src f32 [G][R][C] -> dst bf16 [G][C][R] ----
// srcA covers groups [0,nA), srcB covers [nA,gridDim.z)
__global__ __launch_bounds__(256) void transpose_conv(
    const float* __restrict__ srcA, const float* __restrict__ srcB, int nA,
    unsigned short* __restrict__ dst, int R, int C) {
  __shared__ float t[32][33];
  int g = blockIdx.z;
  const float* s = (g < nA) ? (srcA + (size_t)g * R * C)
                            : (srcB + (size_t)(g - nA) * R * C);
  unsigned short* d = dst + (size_t)g * R * C;
  int c0 = blockIdx.x * 32, r0 = blockIdx.y * 32;
  int tx = threadIdx.x, ty = threadIdx.y;
#pragma unroll
  for (int i = 0; i < 4; ++i)
    t[ty + i * 8][tx] = s[(size_t)(r0 + ty + i * 8) * C + c0 + tx];
  __syncthreads();
#pragma unroll
  for (int i = 0; i < 4; ++i)
    d[(size_t)(c0 + ty + i * 8) * R + r0 + tx] = f2bf(t[tx][ty + i * 8]);
}

// ---- fused rmsnorm + router top2: x f32 -> XnB bf16, idx2/gate2/cnt ----
__global__ __launch_bounds__(256) void rmsnorm_router_k(
    const float* __restrict__ x, const float* __restrict__ nw, const float* __restrict__ Wr,
    unsigned short* __restrict__ xb, int* __restrict__ cnt,
    int* __restrict__ idx2, float* __restrict__ gate2) {
  int t = blockIdx.x, tid = threadIdx.x;
  const float4 v = *(const float4*)(x + (size_t)t * DM + tid * 4);
  float s = v.x * v.x + v.y * v.y + v.z * v.z + v.w * v.w;
#pragma unroll
  for (int o = 32; o; o >>= 1) s += __shfl_down(s, o);
  __shared__ float ps[4];
  if ((tid & 63) == 0) ps[tid >> 6] = s;
  __syncthreads();
  float tot = ps[0] + ps[1] + ps[2] + ps[3];
  float r = rsqrtf(tot * (1.0f / (float)DM) + EPSV);
  const float4 wv = *(const float4*)(nw + tid * 4);
  float4 y;
  y.x = v.x * r * wv.x; y.y = v.y * r * wv.y; y.z = v.z * r * wv.z; y.w = v.w * r * wv.w;
  ushort4 u; u.x = f2bf(y.x); u.y = f2bf(y.y); u.z = f2bf(y.z); u.w = f2bf(y.w);
  *(ushort4*)(xb + (size_t)t * DM + tid * 4) = u;
  // router partials (f32 exact path)
  float pr[8];
#pragma unroll
  for (int e = 0; e < 8; ++e) {
    const float4 w4 = *(const float4*)(Wr + (size_t)e * DM + tid * 4);
    pr[e] = y.x * w4.x + y.y * w4.y + y.z * w4.z + y.w * w4.w;
  }
#pragma unroll
  for (int e = 0; e < 8; ++e)
#pragma unroll
    for (int o = 32; o; o >>= 1) pr[e] += __shfl_down(pr[e], o);
  __shared__ float pw[4 * 8];
  if ((tid & 63) == 0) {
    int w = tid >> 6;
#pragma unroll
    for (int e = 0; e < 8; ++e) pw[w * 8 + e] = pr[e];
  }
  __syncthreads();
  if (tid == 0) {
    float af[8];
#pragma unroll
    for (int e = 0; e < 8; ++e) af[e] = pw[e] + pw[8 + e] + pw[16 + e] + pw[24 + e];
    int e1 = 0; float a1 = af[0];
#pragma unroll
    for (int e = 1; e < 8; ++e) if (af[e] > a1) { a1 = af[e]; e1 = e; }
    int e2 = -1; float a2 = -3.4e38f;
#pragma unroll
    for (int e = 0; e < 8; ++e) if (e != e1 && af[e] > a2) { a2 = af[e]; e2 = e; }
    atomicAdd(&cnt[e1], 1);
    atomicAdd(&cnt[e2], 1);
    idx2[t * 2] = e1; idx2[t * 2 + 1] = e2;
    gate2[t * 2] = a1; gate2[t * 2 + 1] = a2;
  }
}

// ---- fused build tile map + scatter tokens (single block, smem atomics) ----
__global__ __launch_bounds__(256) void buildplace_k(
    const int* __restrict__ cnt, const int* __restrict__ idx2, const float* __restrict__ gate2,
    int* __restrict__ tile_group, int* __restrict__ tok_list, float* __restrict__ gate_list,
    int* __restrict__ slot_of) {
  __shared__ int base_s[8];
  __shared__ int fill_s[8];
  int tid = threadIdx.x;
  if (tid < 8) fill_s[tid] = 0;
  if (tid == 0) {
    for (int i = 0; i < 32; ++i) tile_group[i] = i >> 4;  // shared experts 0,1
    int tile = 32;
    for (int e = 0; e < 8; ++e) {
      base_s[e] = tile * 128;
      int nt = (cnt[e] + 127) >> 7;
      for (int i = 0; i < nt; ++i) tile_group[tile++] = 2 + e;
    }
    for (; tile < MAXTILES; ++tile) tile_group[tile] = -1;
  }
  // default fill
  for (int s = tid; s < MAXSLOTS; s += 256) {
    int tok; float gv;
    if (s < 2048)      { tok = s;        gv = 1.f; }
    else if (s < 4096) { tok = s - 2048; gv = 1.f; }
    else               { tok = -1;       gv = 0.f; }
    tok_list[s] = tok; gate_list[s] = gv;
  }
  __syncthreads();
  for (int t = tid; t < NTOK; t += 256) {
#pragma unroll
    for (int k = 0; k < 2; ++k) {
      int e = idx2[t * 2 + k];
      int pos = atomicAdd(&fill_s[e], 1);
      int slot = base_s[e] + pos;
      tok_list[slot] = t;
      gate_list[slot] = gate2[t * 2 + k];
      slot_of[t * 2 + k] = slot;
    }
  }
}

// ---- grouped GEMM: 128x128 tile, 4 waves, 3-buffer pipelined, counted vmcnt ----
template <int KD, int ND, bool FIRST>
__global__ __launch_bounds__(256) void gemm_k(
    const unsigned short* __restrict__ A, const int* __restrict__ tok_list,
    const int* __restrict__ tile_group, const unsigned short* __restrict__ Bt,
    const float* __restrict__ bias_sh, const float* __restrict__ bias_rt,
    const float* __restrict__ gate_list, unsigned short* __restrict__ Out) {
  constexpr int NK = KD / 32;
  int wg = xcd_swizzle(blockIdx.x, gridDim.x);
  int tile = wg % MAXTILES;
  int bn = (wg / MAXTILES) * 128;
  int g = tile_group[tile];
  if (g < 0) return;
  int tid = threadIdx.x;
  __shared__ unsigned short As[3][128 * 32];
  __shared__ unsigned short Bs[3][128 * 32];
  __shared__ int rows_s[128];
  __shared__ float gates_s[128];
  if (tid < 128) {
    int slot = tile * 128 + tid;
    if (FIRST) {
      int tok = tok_list[slot];
      rows_s[tid] = tok < 0 ? 0 : tok;
    } else {
      rows_s[tid] = slot;
      gates_s[tid] = gate_list[slot];
    }
  }
  __syncthreads();
  int q = tid >> 2, sg = (tid & 3) * 8;
  const unsigned short* srcA0 = A + (size_t)rows_s[q] * KD + sg;
  const unsigned short* srcA1 = A + (size_t)rows_s[64 + q] * KD + sg;
  const unsigned short* bbase = Bt + ((size_t)g * ND + bn) * KD;
  const unsigned short* srcB0 = bbase + (size_t)q * KD + sg;
  const unsigned short* srcB1 = bbase + (size_t)(64 + q) * KD + sg;
  f32x4 acc[4][4];
#pragma unroll
  for (int m = 0; m < 4; ++m)
#pragma unroll
    for (int n = 0; n < 4; ++n) acc[m][n] = (f32x4){0.f, 0.f, 0.f, 0.f};
  int lane = tid & 63, w = tid >> 6;
  int wr = (w >> 1) * 64, wc = (w & 1) * 64;
  int lr = lane & 15, kb = (lane >> 4) * 8;
  int aoff = (wr + lr) * 32 + kb;
  int boff = (wc + lr) * 32 + kb;
  // prologue: stage buffers 0,1
#pragma unroll
  for (int p = 0; p < 2; ++p) {
    int k0 = p * 32;
    async16(srcA0 + k0, (char*)As[p] + tid * 16);
    async16(srcA1 + k0, (char*)As[p] + 4096 + tid * 16);
    async16(srcB0 + k0, (char*)Bs[p] + tid * 16);
    async16(srcB1 + k0, (char*)Bs[p] + 4096 + tid * 16);
  }
  int cur = 0, stg = 2;
  for (int kt = 0; kt < NK; ++kt) {
    // buf[cur] ready when <=4 loads outstanding (only buf[kt+1] in flight);
    // barrier also guarantees all waves are done READING buf[stg]'s old data.
    if (kt < NK - 1)
      asm volatile("s_waitcnt vmcnt(4)\n\ts_barrier" ::: "memory");
    else
      asm volatile("s_waitcnt vmcnt(0)\n\ts_barrier" ::: "memory");
    // issue stage for tile kt+2 (into buf[stg]) — overlaps with compute below
    if (kt + 2 < NK) {
      int k0 = (kt + 2) * 32;
      async16(srcA0 + k0, (char*)As[stg] + tid * 16);
      async16(srcA1 + k0, (char*)As[stg] + 4096 + tid * 16);
      async16(srcB0 + k0, (char*)Bs[stg] + tid * 16);
      async16(srcB1 + k0, (char*)Bs[stg] + 4096 + tid * 16);
    }
    bf16x8 a[4], b[4];
    const unsigned short* pA = &As[cur][0] + aoff;
    const unsigned short* pB = &Bs[cur][0] + boff;
#pragma unroll
    for (int m = 0; m < 4; ++m) a[m] = *(const bf16x8*)(pA + m * 16 * 32);
#pragma unroll
    for (int n = 0; n < 4; ++n) b[n] = *(const bf16x8*)(pB + n * 16 * 32);
#pragma unroll
    for (int m = 0; m < 4; ++m)
#pragma unroll
      for (int n = 0; n < 4; ++n)
        acc[m][n] = __builtin_amdgcn_mfma_f32_16x16x32_bf16(a[m], b[n], acc[m][n], 0, 0, 0);
    cur = (cur == 2) ? 0 : cur + 1;
    stg = (stg == 2) ? 0 : stg + 1;
  }
  const float* bias = (g < 2) ? (bias_sh + (size_t)g * ND) : (bias_rt + (size_t)(g - 2) * ND);
#pragma unroll
  for (int n = 0; n < 4; ++n) {
    int gcol = bn + wc + n * 16 + lr;
    float bv = bias[gcol];
#pragma unroll
    for (int m = 0; m < 4; ++m) {
      int r0 = wr + m * 16 + (lane >> 4) * 4;
#pragma unroll
      for (int j = 0; j < 4; ++j) {
        float v = acc[m][n][j] + bv;
        if (FIRST) {
          v = v / (1.f + expf(-v));  // silu
        } else {
          v *= gates_s[r0 + j];
        }
        Out[(size_t)(tile * 128 + r0 + j) * ND + gcol] = f2bf(v);
      }
    }
  }
}

// ---- combine: out = x + O[shared0] + O[shared1] + O[slot0] + O[slot1] ----
__global__ __launch_bounds__(256) void combine_k(
    const float* __restrict__ x, const unsigned short* __restrict__ O,
    const int* __restrict__ slot_of, float* __restrict__ out) {
  int t = blockIdx.x, tid = threadIdx.x;
  int d = tid * 4;
  int s0 = slot_of[t * 2], s1 = slot_of[t * 2 + 1];
  float4 xv = *(const float4*)(x + (size_t)t * DM + d);
  ushort4 a = *(const ushort4*)(O + (size_t)t * DM + d);
  ushort4 b = *(const ushort4*)(O + (size_t)(2048 + t) * DM + d);
  ushort4 c = *(const ushort4*)(O + (size_t)s0 * DM + d);
  ushort4 e = *(const ushort4*)(O + (size_t)s1 * DM + d);
  float4 o;
  o.x = xv.x + bf2f(a.x) + bf2f(b.x) + bf2f(c.x) + bf2f(e.x);
  o.y = xv.y + bf2f(a.y) + bf2f(b.y) + bf2f(c.y) + bf2f(e.y);
  o.z = xv.z + bf2f(a.z) + bf2f(b.z) + bf2f(c.z) + bf2f(e.z);
  o.w = xv.w + bf2f(a.w) + bf2f(b.w) + bf2f(c.w) + bf2f(e.w);
  *(float4*)(out + (size_t)t * DM + d) = o;
}

extern "C" void kernel_launch(void* const* d_in, const int* in_sizes, int n_in,
                              void* d_out, int out_size, void* d_ws, size_t ws_size,
                              hipStream_t stream) {
  const float* x   = (const float*)d_in[0];
  const float* nw  = (const float*)d_in[1];
  const float* Wr  = (const float*)d_in[2];
  const float* Ws1 = (const float*)d_in[3];
  const float* bs1 = (const float*)d_in[4];
  const float* Ws2 = (const float*)d_in[5];
  const float* bs2 = (const float*)d_in[6];
  const float* W1  = (const float*)d_in[7];
  const float* b1  = (const float*)d_in[8];
  const float* W2  = (const float*)d_in[9];
  const float* b2  = (const float*)d_in[10];
  float* out = (float*)d_out;

  char* ws = (char*)d_ws;
  size_t off = 0;
  auto alloc = [&](size_t n) {
    size_t r = off;
    off += (n + 255) & ~(size_t)255;
    return r;
  };
  unsigned short* XnB  = (unsigned short*)(ws + alloc((size_t)NTOK * DM * 2));
  unsigned short* W1t  = (unsigned short*)(ws + alloc((size_t)NGRP * DH * DM * 2));
  unsigned short* W2t  = (unsigned short*)(ws + alloc((size_t)NGRP * DM * DH * 2));
  unsigned short* Hb   = (unsigned short*)(ws + alloc((size_t)MAXSLOTS * DH * 2));
  unsigned short* Ob   = (unsigned short*)(ws + alloc((size_t)MAXSLOTS * DM * 2));
  int*   cnt       = (int*)(ws + alloc(64));
  int*   idx2      = (int*)(ws + alloc((size_t)NTOK * 2 * 4));
  float* gate2     = (float*)(ws + alloc((size_t)NTOK * 2 * 4));
  int*   tile_group= (int*)(ws + alloc(128 * 4));
  int*   tok_list  = (int*)(ws + alloc((size_t)MAXSLOTS * 4));
  float* gate_list = (float*)(ws + alloc((size_t)MAXSLOTS * 4));
  int*   slot_of   = (int*)(ws + alloc((size_t)NTOK * 2 * 4));

  hipMemsetAsync(cnt, 0, 64, stream);

  // weight convert+transpose: [G][K][N] f32 -> [G][N][K] bf16 (2 launches)
  transpose_conv<<<dim3(44, 32, NGRP), dim3(32, 8), 0, stream>>>(Ws1, W1, 2, W1t, DM, DH);
  transpose_conv<<<dim3(32, 44, NGRP), dim3(32, 8), 0, stream>>>(Ws2, W2, 2, W2t, DH, DM);

  rmsnorm_router_k<<<NTOK, 256, 0, stream>>>(x, nw, Wr, XnB, cnt, idx2, gate2);
  buildplace_k<<<1, 256, 0, stream>>>(cnt, idx2, gate2, tile_group, tok_list, gate_list, slot_of);

  gemm_k<DM, DH, true><<<MAXTILES * (DH / 128), 256, 0, stream>>>(
      XnB, tok_list, tile_group, W1t, bs1, b1, nullptr, Hb);
  gemm_k<DH, DM, false><<<MAXTILES * (DM / 128), 256, 0, stream>>>(
      Hb, tok_list, tile_group, W2t, bs2, b2, gate_list, Ob);

  combine_k<<<NTOK, 256, 0, stream>>>(x, Ob, slot_of, out);
}

// Round 3
// 217.372 us; speedup vs baseline: 1.1479x; 1.0868x over previous
//
#include <hip/hip_runtime.h>
#include <hip/hip_bf16.h>
#include <stdint.h>

// DeepSeek MoE: rmsnorm+router -> grouped expert FFN (2 shared + 8 routed)
// R3: BK=64 double-buffered 2-phase GEMM (stage-first, sync-last), T2 LDS
// swizzle via pre-swizzled global source, tile-major XCD chunking,
// vectorized fused weight transpose.

#define NTOK 2048
#define DM   1024
#define DH   1408
#define NGRP 10
#define EPSV 1.1920928955078125e-7f
#define MAXTILES 72
#define MAXSLOTS (MAXTILES * 128)

typedef __bf16 bf16x8 __attribute__((ext_vector_type(8)));
typedef float  f32x4  __attribute__((ext_vector_type(4)));
typedef unsigned short u16x8 __attribute__((ext_vector_type(8)));

__device__ __forceinline__ void async16(const void* g, void* l) {
  __builtin_amdgcn_global_load_lds(
      (const __attribute__((address_space(1))) unsigned*)g,
      (__attribute__((address_space(3))) unsigned*)l, 16, 0, 0);
}

__device__ __forceinline__ unsigned short f2bf(float f) {
  unsigned u = __builtin_bit_cast(unsigned, f);
  unsigned r = (u + 0x7FFFu + ((u >> 16) & 1u)) >> 16;
  return (unsigned short)r;
}
__device__ __forceinline__ float bf2f(unsigned short h) {
  unsigned u = ((unsigned)h) << 16;
  return __builtin_bit_cast(float, u);
}

// bijective XCD-chunk swizzle (m204): consecutive LOGICAL ids -> same XCD
__device__ __forceinline__ int xcd_swizzle(int id, int nwg) {
  int q = nwg >> 3, r = nwg & 7;
  int xcd = id & 7, idx = id >> 3;
  return (xcd < r ? xcd * (q + 1) : r * (q + 1) + (xcd - r) * q) + idx;
}

// ---- fused vectorized transpose+convert: all weights, one launch ----
// z in [0,10): W1-side  f32 [R=1024][C=1408] -> bf16 [C][R]
// z in [10,20): W2-side f32 [R=1408][C=1024] -> bf16 [C][R]
__global__ __launch_bounds__(256) void transpose_conv(
    const float* __restrict__ Ws1, const float* __restrict__ W1,
    const float* __restrict__ Ws2, const float* __restrict__ W2,
    unsigned short* __restrict__ W1t, unsigned short* __restrict__ W2t) {
  __shared__ float t[64][65];
  int z = blockIdx.z;
  int R, C; const float* s; unsigned short* d;
  if (z < NGRP) {
    R = DM; C = DH;
    s = (z < 2) ? Ws1 + (size_t)z * DM * DH : W1 + (size_t)(z - 2) * DM * DH;
    d = W1t + (size_t)z * DM * DH;
    if (blockIdx.y >= 16) return;  // R/64 = 16
  } else {
    int g = z - NGRP;
    R = DH; C = DM;
    s = (g < 2) ? Ws2 + (size_t)g * DH * DM : W2 + (size_t)(g - 2) * DH * DM;
    d = W2t + (size_t)g * DH * DM;
    if (blockIdx.x >= 16) return;  // C/64 = 16
  }
  int r0 = blockIdx.y * 64, c0 = blockIdx.x * 64;
  int tid = threadIdx.x;
  int rr = tid >> 4, c4 = tid & 15;
#pragma unroll
  for (int p = 0; p < 4; ++p) {
    float4 v = *(const float4*)(s + (size_t)(r0 + p * 16 + rr) * C + c0 + c4 * 4);
    t[p * 16 + rr][c4 * 4 + 0] = v.x;
    t[p * 16 + rr][c4 * 4 + 1] = v.y;
    t[p * 16 + rr][c4 * 4 + 2] = v.z;
    t[p * 16 + rr][c4 * 4 + 3] = v.w;
  }
  __syncthreads();
  int c = tid >> 2;
#pragma unroll
  for (int q = 0; q < 2; ++q) {
    int oct = (tid & 3) * 2 + q;
    u16x8 uv;
#pragma unroll
    for (int j = 0; j < 8; ++j) uv[j] = f2bf(t[oct * 8 + j][c]);
    *(u16x8*)(d + (size_t)(c0 + c) * R + r0 + oct * 8) = uv;
  }
}

// ---- fused rmsnorm + router top2 ----
__global__ __launch_bounds__(256) void rmsnorm_router_k(
    const float* __restrict__ x, const float* __restrict__ nw, const float* __restrict__ Wr,
    unsigned short* __restrict__ xb, int* __restrict__ cnt,
    int* __restrict__ idx2, float* __restrict__ gate2) {
  int t = blockIdx.x, tid = threadIdx.x;
  const float4 v = *(const float4*)(x + (size_t)t * DM + tid * 4);
  float s = v.x * v.x + v.y * v.y + v.z * v.z + v.w * v.w;
#pragma unroll
  for (int o = 32; o; o >>= 1) s += __shfl_down(s, o);
  __shared__ float ps[4];
  if ((tid & 63) == 0) ps[tid >> 6] = s;
  __syncthreads();
  float tot = ps[0] + ps[1] + ps[2] + ps[3];
  float r = rsqrtf(tot * (1.0f / (float)DM) + EPSV);
  const float4 wv = *(const float4*)(nw + tid * 4);
  float4 y;
  y.x = v.x * r * wv.x; y.y = v.y * r * wv.y; y.z = v.z * r * wv.z; y.w = v.w * r * wv.w;
  ushort4 u; u.x = f2bf(y.x); u.y = f2bf(y.y); u.z = f2bf(y.z); u.w = f2bf(y.w);
  *(ushort4*)(xb + (size_t)t * DM + tid * 4) = u;
  float pr[8];
#pragma unroll
  for (int e = 0; e < 8; ++e) {
    const float4 w4 = *(const float4*)(Wr + (size_t)e * DM + tid * 4);
    pr[e] = y.x * w4.x + y.y * w4.y + y.z * w4.z + y.w * w4.w;
  }
#pragma unroll
  for (int e = 0; e < 8; ++e)
#pragma unroll
    for (int o = 32; o; o >>= 1) pr[e] += __shfl_down(pr[e], o);
  __shared__ float pw[4 * 8];
  if ((tid & 63) == 0) {
    int w = tid >> 6;
#pragma unroll
    for (int e = 0; e < 8; ++e) pw[w * 8 + e] = pr[e];
  }
  __syncthreads();
  if (tid == 0) {
    float af[8];
#pragma unroll
    for (int e = 0; e < 8; ++e) af[e] = pw[e] + pw[8 + e] + pw[16 + e] + pw[24 + e];
    int e1 = 0; float a1 = af[0];
#pragma unroll
    for (int e = 1; e < 8; ++e) if (af[e] > a1) { a1 = af[e]; e1 = e; }
    int e2 = -1; float a2 = -3.4e38f;
#pragma unroll
    for (int e = 0; e < 8; ++e) if (e != e1 && af[e] > a2) { a2 = af[e]; e2 = e; }
    atomicAdd(&cnt[e1], 1);
    atomicAdd(&cnt[e2], 1);
    idx2[t * 2] = e1; idx2[t * 2 + 1] = e2;
    gate2[t * 2] = a1; gate2[t * 2 + 1] = a2;
  }
}

// ---- fused build tile map + scatter tokens ----
__global__ __launch_bounds__(256) void buildplace_k(
    const int* __restrict__ cnt, const int* __restrict__ idx2, const float* __restrict__ gate2,
    int* __restrict__ tile_group, int* __restrict__ tok_list, float* __restrict__ gate_list,
    int* __restrict__ slot_of) {
  __shared__ int base_s[8];
  __shared__ int fill_s[8];
  int tid = threadIdx.x;
  if (tid < 8) fill_s[tid] = 0;
  if (tid == 0) {
    for (int i = 0; i < 32; ++i) tile_group[i] = i >> 4;
    int tile = 32;
    for (int e = 0; e < 8; ++e) {
      base_s[e] = tile * 128;
      int nt = (cnt[e] + 127) >> 7;
      for (int i = 0; i < nt; ++i) tile_group[tile++] = 2 + e;
    }
    for (; tile < MAXTILES; ++tile) tile_group[tile] = -1;
  }
  for (int s = tid; s < MAXSLOTS; s += 256) {
    int tok; float gv;
    if (s < 2048)      { tok = s;        gv = 1.f; }
    else if (s < 4096) { tok = s - 2048; gv = 1.f; }
    else               { tok = -1;       gv = 0.f; }
    tok_list[s] = tok; gate_list[s] = gv;
  }
  __syncthreads();
  for (int t = tid; t < NTOK; t += 256) {
#pragma unroll
    for (int k = 0; k < 2; ++k) {
      int e = idx2[t * 2 + k];
      int pos = atomicAdd(&fill_s[e], 1);
      int slot = base_s[e] + pos;
      tok_list[slot] = t;
      gate_list[slot] = gate2[t * 2 + k];
      slot_of[t * 2 + k] = slot;
    }
  }
}

// ---- grouped GEMM: 128x128 tile, BK=64, dbuf 2-phase, src-swizzled LDS ----
template <int KD, int ND, bool FIRST>
__global__ __launch_bounds__(256) void gemm_k(
    const unsigned short* __restrict__ A, const int* __restrict__ tok_list,
    const int* __restrict__ tile_group, const unsigned short* __restrict__ Bt,
    const float* __restrict__ bias_sh, const float* __restrict__ bias_rt,
    const float* __restrict__ gate_list, unsigned short* __restrict__ Out) {
  constexpr int NK = KD / 64;
  constexpr int NBN = ND / 128;
  int wg = xcd_swizzle(blockIdx.x, MAXTILES * NBN);
  int tile = wg / NBN;
  int bn = (wg % NBN) * 128;
  int g = tile_group[tile];
  if (g < 0) return;
  int tid = threadIdx.x;
  __shared__ unsigned short As[2][8192];  // [128 rows][64 k] bf16, col16-swizzled
  __shared__ unsigned short Bs[2][8192];
  __shared__ int rows_s[128];
  __shared__ float gates_s[128];
  if (tid < 128) {
    int slot = tile * 128 + tid;
    if (FIRST) {
      int tok = tok_list[slot];
      rows_s[tid] = tok < 0 ? 0 : tok;
    } else {
      rows_s[tid] = slot;
      gates_s[tid] = gate_list[slot];
    }
  }
  __syncthreads();
  // staging: dest row = p*32 + tid>>3, dest col16 = tid&7 (linear, tid*16 bytes)
  // value stored at (row,c16) = global (row, c16 ^ (row&7))  [T2 involution]
  int drow = tid >> 3;
  int sc16 = (tid & 7) ^ (drow & 7);
  const unsigned short* bbase = Bt + ((size_t)g * ND + bn) * KD;
  const unsigned short* aSrc[4];
  const unsigned short* bSrc[4];
#pragma unroll
  for (int p = 0; p < 4; ++p) {
    aSrc[p] = A + (size_t)rows_s[p * 32 + drow] * KD + sc16 * 8;
    bSrc[p] = bbase + (size_t)(p * 32 + drow) * KD + sc16 * 8;
  }
  int lane = tid & 63, w = tid >> 6;
  int wr = (w >> 1) * 64, wc = (w & 1) * 64;
  int lr = lane & 15, hi = lane >> 4, e = lr & 7;
  int offk0 = ((0 + hi) ^ e) * 16;  // byte offset of k-chunk within row, ks=0
  int offk1 = ((4 + hi) ^ e) * 16;  // ks=1
  f32x4 acc[4][4];
#pragma unroll
  for (int m = 0; m < 4; ++m)
#pragma unroll
    for (int n = 0; n < 4; ++n) acc[m][n] = (f32x4){0.f, 0.f, 0.f, 0.f};

  auto stage = [&](int buf, int kt) {
    int k0 = kt * 64;
#pragma unroll
    for (int p = 0; p < 4; ++p) {
      async16(aSrc[p] + k0, (char*)&As[buf][0] + p * 4096 + tid * 16);
      async16(bSrc[p] + k0, (char*)&Bs[buf][0] + p * 4096 + tid * 16);
    }
  };
  stage(0, 0);
  __syncthreads();  // buf0 staged (drains vmcnt)
  int cur = 0;
  for (int kt = 0; kt < NK; ++kt) {
    if (kt + 1 < NK) stage(cur ^ 1, kt + 1);  // issue-first: overlaps compute
    const char* aC = (const char*)&As[cur][0] + (wr + lr) * 128;
    const char* bC = (const char*)&Bs[cur][0] + (wc + lr) * 128;
#pragma unroll
    for (int ks = 0; ks < 2; ++ks) {
      int ofk = ks ? offk1 : offk0;
      bf16x8 a[4], b[4];
#pragma unroll
      for (int m = 0; m < 4; ++m) a[m] = *(const bf16x8*)(aC + m * 2048 + ofk);
#pragma unroll
      for (int n = 0; n < 4; ++n) b[n] = *(const bf16x8*)(bC + n * 2048 + ofk);
#pragma unroll
      for (int m = 0; m < 4; ++m)
#pragma unroll
        for (int n = 0; n < 4; ++n)
          acc[m][n] = __builtin_amdgcn_mfma_f32_16x16x32_bf16(a[m], b[n], acc[m][n], 0, 0, 0);
    }
    __syncthreads();  // drains vmcnt(0): next buffer staged; all reads done
    cur ^= 1;
  }
  const float* bias = (g < 2) ? (bias_sh + (size_t)g * ND) : (bias_rt + (size_t)(g - 2) * ND);
#pragma unroll
  for (int n = 0; n < 4; ++n) {
    int gcol = bn + wc + n * 16 + lr;
    float bv = bias[gcol];
#pragma unroll
    for (int m = 0; m < 4; ++m) {
      int r0 = wr + m * 16 + hi * 4;
#pragma unroll
      for (int j = 0; j < 4; ++j) {
        float v = acc[m][n][j] + bv;
        if (FIRST) {
          v = v / (1.f + expf(-v));  // silu
        } else {
          v *= gates_s[r0 + j];
        }
        Out[(size_t)(tile * 128 + r0 + j) * ND + gcol] = f2bf(v);
      }
    }
  }
}

// ---- combine ----
__global__ __launch_bounds__(256) void combine_k(
    const float* __restrict__ x, const unsigned short* __restrict__ O,
    const int* __restrict__ slot_of, float* __restrict__ out) {
  int t = blockIdx.x, tid = threadIdx.x;
  int d = tid * 4;
  int s0 = slot_of[t * 2], s1 = slot_of[t * 2 + 1];
  float4 xv = *(const float4*)(x + (size_t)t * DM + d);
  ushort4 a = *(const ushort4*)(O + (size_t)t * DM + d);
  ushort4 b = *(const ushort4*)(O + (size_t)(2048 + t) * DM + d);
  ushort4 c = *(const ushort4*)(O + (size_t)s0 * DM + d);
  ushort4 e = *(const ushort4*)(O + (size_t)s1 * DM + d);
  float4 o;
  o.x = xv.x + bf2f(a.x) + bf2f(b.x) + bf2f(c.x) + bf2f(e.x);
  o.y = xv.y + bf2f(a.y) + bf2f(b.y) + bf2f(c.y) + bf2f(e.y);
  o.z = xv.z + bf2f(a.z) + bf2f(b.z) + bf2f(c.z) + bf2f(e.z);
  o.w = xv.w + bf2f(a.w) + bf2f(b.w) + bf2f(c.w) + bf2f(e.w);
  *(float4*)(out + (size_t)t * DM + d) = o;
}

extern "C" void kernel_launch(void* const* d_in, const int* in_sizes, int n_in,
                              void* d_out, int out_size, void* d_ws, size_t ws_size,
                              hipStream_t stream) {
  const float* x   = (const float*)d_in[0];
  const float* nw  = (const float*)d_in[1];
  const float* Wr  = (const float*)d_in[2];
  const float* Ws1 = (const float*)d_in[3];
  const float* bs1 = (const float*)d_in[4];
  const float* Ws2 = (const float*)d_in[5];
  const float* bs2 = (const float*)d_in[6];
  const float* W1  = (const float*)d_in[7];
  const float* b1  = (const float*)d_in[8];
  const float* W2  = (const float*)d_in[9];
  const float* b2  = (const float*)d_in[10];
  float* out = (float*)d_out;

  char* ws = (char*)d_ws;
  size_t off = 0;
  auto alloc = [&](size_t n) {
    size_t r = off;
    off += (n + 255) & ~(size_t)255;
    return r;
  };
  unsigned short* XnB  = (unsigned short*)(ws + alloc((size_t)NTOK * DM * 2));
  unsigned short* W1t  = (unsigned short*)(ws + alloc((size_t)NGRP * DH * DM * 2));
  unsigned short* W2t  = (unsigned short*)(ws + alloc((size_t)NGRP * DM * DH * 2));
  unsigned short* Hb   = (unsigned short*)(ws + alloc((size_t)MAXSLOTS * DH * 2));
  unsigned short* Ob   = (unsigned short*)(ws + alloc((size_t)MAXSLOTS * DM * 2));
  int*   cnt       = (int*)(ws + alloc(64));
  int*   idx2      = (int*)(ws + alloc((size_t)NTOK * 2 * 4));
  float* gate2     = (float*)(ws + alloc((size_t)NTOK * 2 * 4));
  int*   tile_group= (int*)(ws + alloc(128 * 4));
  int*   tok_list  = (int*)(ws + alloc((size_t)MAXSLOTS * 4));
  float* gate_list = (float*)(ws + alloc((size_t)MAXSLOTS * 4));
  int*   slot_of   = (int*)(ws + alloc((size_t)NTOK * 2 * 4));

  hipMemsetAsync(cnt, 0, 64, stream);

  transpose_conv<<<dim3(22, 22, 2 * NGRP), 256, 0, stream>>>(Ws1, W1, Ws2, W2, W1t, W2t);

  rmsnorm_router_k<<<NTOK, 256, 0, stream>>>(x, nw, Wr, XnB, cnt, idx2, gate2);
  buildplace_k<<<1, 256, 0, stream>>>(cnt, idx2, gate2, tile_group, tok_list, gate_list, slot_of);

  gemm_k<DM, DH, true><<<MAXTILES * (DH / 128), 256, 0, stream>>>(
      XnB, tok_list, tile_group, W1t, bs1, b1, nullptr, Hb);
  gemm_k<DH, DM, false><<<MAXTILES * (DM / 128), 256, 0, stream>>>(
      Hb, tok_list, tile_group, W2t, bs2, b2, gate_list, Ob);

  combine_k<<<NTOK, 256, 0, stream>>>(x, Ob, slot_of, out);
}